// Round 3
// baseline (130.697 us; speedup 1.0000x reference)
//
#include <hip/hip_runtime.h>
#include <math.h>

// SpectralPooling: out = Re(ifft3_32(pad32(crop24(Re(fft3_48(x))))))  per (b,c) volume.
// bc = 256 volumes of 48^3 fp32 -> 256 x 32^3 fp32.
//
// r12: MONO-KERNEL. Dependency chain is per-bc only -> one block per bc runs all
// three phases with __syncthreads() phase boundaries. No inter-kernel launches/drains,
// V[bc]/W[bc] round-trip through the own-XCD L2, and the kernel becomes visible in
// rocprof top-5 (fills no longer mask it).
//  phase1 (48 slabs n1): D1 = T1*X ; D2 = D1*T2t ; recombine -> V[bc] (global, L2-hot)
//  phase2 (24 k3):  [Wr;Wi](64x24) = M_comb(64x96) * [Vr;Vi](96x24) -> W[bc] (global, L2-hot)
//  phase3 (32 m1):  [Zr;Zi] = MB2*[Wr;Wi] ; out = Z*TB3
// Split-f16 everywhere: P = Ahi*Bhi + Ahi*Blo + Alo*Bhi (~22 mantissa bits).
// GEMM bodies / frag layouts / barrier schedules verbatim from r11 (verified).
//
// d_ws: float2 V[256][24][48][24] (56,623,104 B) then float2 W[256][32][24][24].

#define TWO_PI_48 0.13089969389957470f
#define TWO_PI_32 0.19634954084936207f
#define NORM_F    1.6611664e-05f         // 1/(48^1.5 * 32^1.5)

typedef _Float16 half8  __attribute__((ext_vector_type(8)));
typedef _Float16 half4v __attribute__((ext_vector_type(4)));
typedef float    f32x4  __attribute__((ext_vector_type(4)));

// Frag-layout tables: [hi/lo][tile][kstep][lane][j]
// A-frag element = A[tile*16 + (l&15)][ks*32 + (l>>4)*8 + j]
// B-frag element = B[ks*32 + (l>>4)*8 + j][tile*16 + (l&15)]
__device__ _Float16 T1frag[2][3][2][64][8];
__device__ _Float16 T2frag[2][3][2][64][8];
__device__ __align__(16) _Float16 TK2frag[2][4][3][64][8];  // M_comb 64x96
__device__ __align__(16) _Float16 MB2frag[2][4][2][64][8];  // 64x48 (pad 64)
__device__ __align__(16) _Float16 TB3frag[2][2][2][64][8];  // 48(pad64)x32

__device__ int g_twdone = 0;   // lazy-init flag (module-lifetime, set post-init)

__global__ void k_init_tw() {
  if (g_twdone) return;                             // tables already built (pure consts)
  const int idx = blockIdx.x * 256 + threadIdx.x;   // 0..15359
  if (idx < 3072) {                                 // K1 tables (verified r5)
    const int j  = idx & 7;
    const int l  = (idx >> 3) & 63;
    const int ks = (idx >> 9) & 1;
    const int t  = idx >> 10;
    const int k  = ks * 32 + (l >> 4) * 8 + j;
    {
      const int m = t * 16 + (l & 15);
      float v = 0.f;
      if (k < 48) {
        const float a = (float)(((m % 24) * k) % 48) * TWO_PI_48;
        v = (m < 24) ? cosf(a) : -sinf(a);
      }
      const _Float16 h = (_Float16)v;
      T1frag[0][t][ks][l][j] = h;
      T1frag[1][t][ks][l][j] = (_Float16)(v - (float)h);
    }
    {
      const int c = t * 16 + (l & 15);
      float v = 0.f;
      if (k < 48) {
        const float a = (float)(((c % 24) * k) % 48) * TWO_PI_48;
        v = (c < 24) ? cosf(a) : sinf(a);
      }
      const _Float16 h = (_Float16)v;
      T2frag[0][t][ks][l][j] = h;
      T2frag[1][t][ks][l][j] = (_Float16)(v - (float)h);
    }
  } else if (idx < 3072 + 6144) {                   // K2: M_comb (A3+B1 fused)
    const int local = idx - 3072;
    const int j = local & 7, l = (local >> 3) & 63;
    const int rest = local >> 9;                    // 0..11
    const int ks = rest % 3, mt = rest / 3;
    const int m   = mt * 16 + (l & 15);             // 0..63
    const int kap = ks * 32 + (l >> 4) * 8 + j;     // 0..95
    const int n1  = kap % 48;
    const bool isVi = kap >= 48;
    const int m1  = m & 31;
    const bool isWi = m >= 32;
    float acc = 0.f;
    for (int k1 = 0; k1 < 24; ++k1) {
      float s32v, c32v, s48v, c48v;
      sincosf((float)((k1 * m1) % 32) * TWO_PI_32, &s32v, &c32v);
      sincosf((float)((k1 * n1) % 48) * TWO_PI_48, &s48v, &c48v);
      acc = fmaf(isWi ? s32v : c32v, isVi ? s48v : c48v, acc);
    }
    const _Float16 h = (_Float16)acc;
    TK2frag[0][mt][ks][l][j] = h;
    TK2frag[1][mt][ks][l][j] = (_Float16)(acc - (float)h);
  } else if (idx < 3072 + 6144 + 4096) {            // K3: MB2 (B2 A-matrix)
    const int local = idx - (3072 + 6144);
    const int j = local & 7, l = (local >> 3) & 63;
    const int rest = local >> 9;                    // 0..7
    const int ks = rest & 1, mt = rest >> 1;
    const int m   = mt * 16 + (l & 15);             // 0..63
    const int kap = ks * 32 + (l >> 4) * 8 + j;     // 0..63
    float v = 0.f;
    if (kap < 48) {
      const int k2 = kap % 24;
      const int m2 = m & 31;
      float s, c;
      sincosf((float)((k2 * m2) % 32) * TWO_PI_32, &s, &c);
      if (m < 32) v = (kap < 24) ? c : -s;   // Zr = sum Wr*c - Wi*s
      else        v = (kap < 24) ? s :  c;   // Zi = sum Wr*s + Wi*c
    }
    const _Float16 h = (_Float16)v;
    MB2frag[0][mt][ks][l][j] = h;
    MB2frag[1][mt][ks][l][j] = (_Float16)(v - (float)h);
  } else if (idx < 15360) {                         // K3: TB3 (B3 B-matrix)
    const int local = idx - (3072 + 6144 + 4096);
    const int j = local & 7, l = (local >> 3) & 63;
    const int rest = local >> 9;                    // 0..3
    const int ks = rest & 1, nt = rest >> 1;
    const int m3  = nt * 16 + (l & 15);             // col 0..31
    const int kap = ks * 32 + (l >> 4) * 8 + j;     // 0..63
    float v = 0.f;
    if (kap < 48) {
      const int k3 = kap % 24;
      float s, c;
      sincosf((float)((k3 * m3) % 32) * TWO_PI_32, &s, &c);
      v = (kap < 24) ? c : -s;               // out = sum Zr*c - Zi*s
    }
    const _Float16 h = (_Float16)v;
    TB3frag[0][nt][ks][l][j] = h;
    TB3frag[1][nt][ks][l][j] = (_Float16)(v - (float)h);
  }
}

__device__ inline void split8(const float* qf, half8& h, half8& lo) {
#pragma unroll
  for (int j = 0; j < 8; ++j) {
    const _Float16 hh = (_Float16)qf[j];
    h[j]  = hh;
    lo[j] = (_Float16)(qf[j] - (float)hh);
  }
}

// ---------------- mono kernel: one block per bc, 192 threads ----------------
// LDS pool aliasing (sequential phases, barrier-fenced):
//   phase1: arenaA = pool[0:13824], arenaB = pool[13824:27648]  (ping-pong X/D2 vs U)
//   phase2: Bb = (float*)pool, 48*100*4 = 19200 B
//   phase3: Bt = (float*)pool (8704 B), Zb = (float*)(pool+8704) (8704 B)
__global__ __launch_bounds__(192) void k_mono(const float* __restrict__ x,
                                              float2* __restrict__ V,
                                              float2* __restrict__ W,
                                              float* __restrict__ out) {
  const int bc   = blockIdx.x;   // 0..255
  const int tid  = threadIdx.x;
  const int lane = tid & 63;
  const int w    = tid >> 6;     // 0..2

  __shared__ __align__(16) unsigned char pool[27648];
  unsigned char* arenaA = pool;
  unsigned char* arenaB = pool + 13824;

  const int kb    = (lane >> 4) * 8;
  const int c16   = lane & 15;
  const int cc    = w * 16 + c16;       // 0..47
  const int rbase = (lane >> 4) * 4;

  // ================= PHASE 1: 48 slabs (n1 = 0..47) =================
  {
    // hoist twiddle fragments (phase-local)
    half8 t1h[3][2], t1l[3][2];
#pragma unroll
    for (int mt = 0; mt < 3; ++mt)
#pragma unroll
      for (int ks = 0; ks < 2; ++ks) {
        t1h[mt][ks] = *(const half8*)&T1frag[0][mt][ks][lane][0];
        t1l[mt][ks] = *(const half8*)&T1frag[1][mt][ks][lane][0];
      }
    half8 t2h[2], t2l[2];
#pragma unroll
    for (int ks = 0; ks < 2; ++ks) {
      t2h[ks] = *(const half8*)&T2frag[0][w][ks][lane][0];
      t2l[ks] = *(const half8*)&T2frag[1][w][ks][lane][0];
    }

    const int k2e  = tid % 24;
    const int k30e = (tid / 24) * 3;

    // prologue prefetch (n1 = 0)
    float4 xr0, xr1, xr2;
    {
      const float4* g4 = (const float4*)(x + ((size_t)(bc * 48)) * 2304);
      xr0 = g4[tid]; xr1 = g4[tid + 192]; xr2 = g4[tid + 384];
    }

    // Race audit (verbatim r11 schedule, now 48 iters):
    //  stage(g) writes arena[g&1] (was aU(g-1), readers GEMM2(g-1) all pre-b3(g-1);
    //    each wave stages after its own epilogue(g-1) which reads the OTHER arena). OK.
    //  Udump(g) writes arena[1-(g&1)] (= aX(g-1) where epilogue(g-1) reads D2);
    //    Udump is post-b1(g), every wave passed b1 only after its epilogue(g-1). OK.
    //  D2dump(g) writes aX(g); prior readers GEMM1(g) X-reads all pre-b2(g). OK.
    for (int g = 0; g < 48; ++g) {
      const int n1 = g;
      unsigned char* aX = (g & 1) ? arenaB : arenaA;
      unsigned char* aU = (g & 1) ? arenaA : arenaB;
      _Float16* Xh = (_Float16*)aX;             // [48][72]
      _Float16* Xl = (_Float16*)(aX + 6912);
      float*    D2 = (float*)aX;                // [48][68] f32 view
      _Float16* Uh = (_Float16*)aU;
      _Float16* Ul = (_Float16*)(aU + 6912);

      // stage X from prefetched regs
      {
        const float4 fr[3] = {xr0, xr1, xr2};
#pragma unroll
        for (int jj = 0; jj < 3; ++jj) {
          const int i4 = tid + 192 * jj;             // 0..575
          const int r = i4 / 12, c4 = i4 % 12;
          const float4 f = fr[jj];
          const _Float16 h0 = (_Float16)f.x, h1 = (_Float16)f.y,
                         h2 = (_Float16)f.z, h3 = (_Float16)f.w;
          const half4v hv = {h0, h1, h2, h3};
          const half4v lv = {(_Float16)(f.x - (float)h0), (_Float16)(f.y - (float)h1),
                             (_Float16)(f.z - (float)h2), (_Float16)(f.w - (float)h3)};
          *(half4v*)&Xh[r * 72 + c4 * 4] = hv;
          *(half4v*)&Xl[r * 72 + c4 * 4] = lv;
        }
      }
      // zero X pad cols 48..63 (arena held D2/U junk)
      if (tid < 96) {
        _Float16* p = (tid < 48 ? Xh : Xl) + (tid % 48) * 72 + 48;
        *(half8*)&p[0] = (half8){};
        *(half8*)&p[8] = (half8){};
      }
      // prefetch next slab
      if (g < 47) {
        const float4* g4 = (const float4*)(x + ((size_t)(bc * 48 + n1 + 1)) * 2304);
        xr0 = g4[tid]; xr1 = g4[tid + 192]; xr2 = g4[tid + 384];
      }
      __syncthreads();   // b1: X staged

      // ---- GEMM1: D1 = T1 * X ----
      f32x4 acc0 = {}, acc1 = {}, acc2 = {};
#pragma unroll
      for (int ks = 0; ks < 2; ++ks) {
        const half8 bh = *(const half8*)&Xh[(w * 16 + c16) * 72 + ks * 32 + kb];
        const half8 bl = *(const half8*)&Xl[(w * 16 + c16) * 72 + ks * 32 + kb];
#pragma unroll
        for (int mt = 0; mt < 3; ++mt) {
          f32x4& acc = (mt == 0) ? acc0 : (mt == 1) ? acc1 : acc2;
          acc = __builtin_amdgcn_mfma_f32_16x16x32_f16(t1h[mt][ks], bh, acc, 0, 0, 0);
          acc = __builtin_amdgcn_mfma_f32_16x16x32_f16(t1h[mt][ks], bl, acc, 0, 0, 0);
          acc = __builtin_amdgcn_mfma_f32_16x16x32_f16(t1l[mt][ks], bh, acc, 0, 0, 0);
        }
      }

      // U dump
#pragma unroll
      for (int mt = 0; mt < 3; ++mt) {
        const int r0 = mt * 16 + (lane >> 4) * 4;
        const f32x4 acc = (mt == 0) ? acc0 : (mt == 1) ? acc1 : acc2;
#pragma unroll
        for (int r = 0; r < 4; ++r) {
          const float v = acc[r];
          const _Float16 h = (_Float16)v;
          Uh[(r0 + r) * 72 + cc] = h;
          Ul[(r0 + r) * 72 + cc] = (_Float16)(v - (float)h);
        }
      }
      // zero U pad cols 48..63
      if (tid < 96) {
        _Float16* p = (tid < 48 ? Uh : Ul) + (tid % 48) * 72 + 48;
        *(half8*)&p[0] = (half8){};
        *(half8*)&p[8] = (half8){};
      }
      __syncthreads();   // b2: U visible (and all X reads done)

      // ---- GEMM2: D2 = U * T2t ----
      f32x4 d20 = {}, d21 = {}, d22 = {};
#pragma unroll
      for (int ks = 0; ks < 2; ++ks) {
#pragma unroll
        for (int mt = 0; mt < 3; ++mt) {
          const half8 ah = *(const half8*)&Uh[(mt * 16 + c16) * 72 + ks * 32 + kb];
          const half8 al = *(const half8*)&Ul[(mt * 16 + c16) * 72 + ks * 32 + kb];
          f32x4& acc = (mt == 0) ? d20 : (mt == 1) ? d21 : d22;
          acc = __builtin_amdgcn_mfma_f32_16x16x32_f16(ah, t2h[ks], acc, 0, 0, 0);
          acc = __builtin_amdgcn_mfma_f32_16x16x32_f16(ah, t2l[ks], acc, 0, 0, 0);
          acc = __builtin_amdgcn_mfma_f32_16x16x32_f16(al, t2h[ks], acc, 0, 0, 0);
        }
      }

      // D2 dump into aX arena (X dead since b2)
#pragma unroll
      for (int mt = 0; mt < 3; ++mt) {
        const int r0 = mt * 16 + (lane >> 4) * 4;
        const f32x4 acc = (mt == 0) ? d20 : (mt == 1) ? d21 : d22;
#pragma unroll
        for (int r = 0; r < 4; ++r) D2[(r0 + r) * 68 + cc] = acc[r];
      }
      __syncthreads();   // b3: D2 visible (all U reads done)

      // epilogue: recombine -> V[bc][k3][n1][k2]  (overlaps next iter's stage)
      float2* Vp = V + (size_t)(bc * 24) * 1152 + (size_t)n1 * 24 + k2e;
#pragma unroll
      for (int q = 0; q < 3; ++q) {
        const int k3 = k30e + q;
        const float grr = D2[k3 * 68 + k2e];
        const float gis = D2[(k3 + 24) * 68 + k2e + 24];
        const float gir = D2[(k3 + 24) * 68 + k2e];
        const float grs = D2[k3 * 68 + k2e + 24];
        Vp[(size_t)k3 * 1152] = make_float2(grr + gis, gir - grs);
      }
      // no trailing barrier: next stage writes the OTHER arena.
    }
  }

  __syncthreads();   // PHASE BOUNDARY 1->2: V[bc] visible block-wide; pool reads done.

  // ================= PHASE 2: 24 k3-GEMMs =================
  // GEMM shape M=64 (m1 r/i), K=96 (n1 r/i), N=24 real cols (cols 24..47 garbage:
  // stale LDS; MFMA output col n depends only on B col n -> garbage stays in
  // discarded columns; threads with cc>=24 never store).
  {
    float* Bb = (float*)pool;   // [col 0..47][kap 0..95] stride 100

    half8 kth[4][3], ktl[4][3];
#pragma unroll
    for (int mt = 0; mt < 4; ++mt)
#pragma unroll
      for (int ks = 0; ks < 3; ++ks) {
        kth[mt][ks] = *(const half8*)&TK2frag[0][mt][ks][lane][0];
        ktl[mt][ks] = *(const half8*)&TK2frag[1][mt][ks][lane][0];
      }

    // prologue prefetch (k3=0): 3 float4/thread = 576 float4 = V[bc][0] slab
    float4 vr0, vr1, vr2;
    {
      const float4* g0 = (const float4*)(V + (size_t)(bc * 24) * 1152);
      vr0 = g0[tid]; vr1 = g0[tid + 192]; vr2 = g0[tid + 384];
    }

    for (int k3 = 0; k3 < 24; ++k3) {
      if (k3) __syncthreads();   // prev iteration's Bb reads done

      // stage cols 0..23 from prefetched regs
      {
        const float4 fr[3] = {vr0, vr1, vr2};
#pragma unroll
        for (int jj = 0; jj < 3; ++jj) {
          const int r = tid + 192 * jj;     // 0..575 ; n1 = r/12, k2-pair = r%12
          const int n1 = r / 12, c4 = r % 12;
          const float4 f = fr[jj];
          float* bp = &Bb[(c4 * 2) * 100 + n1];
          bp[0]   = f.x;  bp[48]  = f.y;    // col 2*c4:   Vr[n1], Vi[n1]
          bp[100] = f.z;  bp[148] = f.w;    // col 2*c4+1
        }
      }
      // prefetch next k3 slab
      if (k3 < 23) {
        const float4* g0 = (const float4*)(V + (size_t)(bc * 24 + k3 + 1) * 1152);
        vr0 = g0[tid]; vr1 = g0[tid + 192]; vr2 = g0[tid + 384];
      }
      __syncthreads();

      f32x4 a0 = {}, a1 = {}, a2 = {}, a3 = {};
#pragma unroll
      for (int ks = 0; ks < 3; ++ks) {
        const float4 q0 = *(const float4*)&Bb[cc * 100 + ks * 32 + kb];
        const float4 q1 = *(const float4*)&Bb[cc * 100 + ks * 32 + kb + 4];
        const float qf[8] = {q0.x, q0.y, q0.z, q0.w, q1.x, q1.y, q1.z, q1.w};
        half8 bh, bl;
        split8(qf, bh, bl);
#pragma unroll
        for (int mt = 0; mt < 4; ++mt) {
          f32x4& acc = (mt == 0) ? a0 : (mt == 1) ? a1 : (mt == 2) ? a2 : a3;
          acc = __builtin_amdgcn_mfma_f32_16x16x32_f16(kth[mt][ks], bh, acc, 0, 0, 0);
          acc = __builtin_amdgcn_mfma_f32_16x16x32_f16(kth[mt][ks], bl, acc, 0, 0, 0);
          acc = __builtin_amdgcn_mfma_f32_16x16x32_f16(ktl[mt][ks], bh, acc, 0, 0, 0);
        }
      }

      // epilogue: rows 0..31 = Wr, rows 32..63 = Wi -> W[bc][m1][k3][k2]
      if (cc < 24) {
        float2* wp = W + (size_t)bc * 18432 + (size_t)k3 * 24 + cc;
#pragma unroll
        for (int mt = 0; mt < 2; ++mt) {
          const f32x4 wr = (mt == 0) ? a0 : a1;
          const f32x4 wi = (mt == 0) ? a2 : a3;
#pragma unroll
          for (int r = 0; r < 4; ++r) {
            const int m1 = mt * 16 + rbase + r;
            wp[(size_t)m1 * 576] = make_float2(wr[r], wi[r]);
          }
        }
      }
    }
  }

  __syncthreads();   // PHASE BOUNDARY 2->3: W[bc] visible; pool (Bb) reads done.

  // ================= PHASE 3: 32 m1-GEMMs =================
  // Waves 0-1 compute (K3 verbatim); wave 2 helps stage only (guards are
  // wave-uniform: w==2 is exactly tid 128..191). Barriers hit by ALL waves.
  {
    float* Bt = (float*)pool;            // [col=k3 0..31][kap 0..67]
    float* Zb = (float*)(pool + 8704);   // [m2 0..31][kap 0..67]

    half8 mbh[4][2], mbl[4][2];
#pragma unroll
    for (int mt = 0; mt < 4; ++mt)
#pragma unroll
      for (int ks = 0; ks < 2; ++ks) {
        mbh[mt][ks] = *(const half8*)&MB2frag[0][mt][ks][lane][0];
        mbl[mt][ks] = *(const half8*)&MB2frag[1][mt][ks][lane][0];
      }
    const int wn = (w < 2) ? w : 0;      // clamp table index for wave 2 (unused)
    half8 tb3h[2], tb3l[2];
#pragma unroll
    for (int ks = 0; ks < 2; ++ks) {
      tb3h[ks] = *(const half8*)&TB3frag[0][wn][ks][lane][0];
      tb3l[ks] = *(const half8*)&TB3frag[1][wn][ks][lane][0];
    }

    // zero pad regions ONCE (pool held Bb junk)
    for (int i = tid; i < 8 * 68; i += 192)  Bt[(24 + i / 68) * 68 + (i % 68)] = 0.f;
    for (int i = tid; i < 24 * 20; i += 192) Bt[(i / 20) * 68 + 48 + (i % 20)] = 0.f;
    for (int i = tid; i < 32 * 20; i += 192) Zb[(i / 20) * 68 + 48 + (i % 20)] = 0.f;

    // prologue prefetch (m1=0): 288 contiguous float4 = W[bc][0]
    float4 vr0, vr1;
    {
      const float4* g4 = (const float4*)(W + (size_t)bc * 18432);
      vr0 = g4[tid];
      if (tid < 96) vr1 = g4[tid + 192];
    }

    // Race audit (r11 K3 schedule): stage(m1) writes Bt, readers GEMM1(m1-1) all
    // pre-b2(m1-1). relayout(m1) writes Zb post-b1(m1), readers GEMM2(m1-1) all
    // pre-b1(m1) in each wave's program order (wave2 skips GEMM2, trivially ok).
    // First iter: zero-writes fenced by b1(0).
    for (int m1 = 0; m1 < 32; ++m1) {
      // stage Bt from prefetched regs (288 float4 over 192 threads)
      {
#pragma unroll
        for (int jj = 0; jj < 2; ++jj) {
          const int i4 = tid + 192 * jj;
          if (jj == 0 || tid < 96) {
            const int k3 = i4 / 12, c4 = i4 % 12;
            const float4 f = (jj == 0) ? vr0 : vr1;
            Bt[k3 * 68 + 2 * c4]          = f.x;
            Bt[k3 * 68 + 24 + 2 * c4]     = f.y;
            Bt[k3 * 68 + 2 * c4 + 1]      = f.z;
            Bt[k3 * 68 + 24 + 2 * c4 + 1] = f.w;
          }
        }
      }
      // prefetch next m1
      if (m1 < 31) {
        const float4* g4 = (const float4*)(W + (size_t)bc * 18432 + (size_t)(m1 + 1) * 576);
        vr0 = g4[tid];
        if (tid < 96) vr1 = g4[tid + 192];
      }
      __syncthreads();   // b1: Bt staged (and prev GEMM2's Zb reads done)

      if (w < 2) {
        // GEMM1: [Zr;Zi](64 x k3) = MB2 * [Wr;Wi]
        f32x4 z0 = {}, z1 = {}, z2 = {}, z3 = {};
#pragma unroll
        for (int ks = 0; ks < 2; ++ks) {
          const float4 q0 = *(const float4*)&Bt[cc * 68 + ks * 32 + kb];
          const float4 q1 = *(const float4*)&Bt[cc * 68 + ks * 32 + kb + 4];
          const float qf[8] = {q0.x, q0.y, q0.z, q0.w, q1.x, q1.y, q1.z, q1.w};
          half8 bh, bl;
          split8(qf, bh, bl);
#pragma unroll
          for (int mt = 0; mt < 4; ++mt) {
            f32x4& acc = (mt == 0) ? z0 : (mt == 1) ? z1 : (mt == 2) ? z2 : z3;
            acc = __builtin_amdgcn_mfma_f32_16x16x32_f16(mbh[mt][ks], bh, acc, 0, 0, 0);
            acc = __builtin_amdgcn_mfma_f32_16x16x32_f16(mbh[mt][ks], bl, acc, 0, 0, 0);
            acc = __builtin_amdgcn_mfma_f32_16x16x32_f16(mbl[mt][ks], bh, acc, 0, 0, 0);
          }
        }
        // relayout: Zb[m2][k3] = Zr, Zb[m2][24+k3] = Zi
        if (cc < 24) {
#pragma unroll
          for (int mt = 0; mt < 4; ++mt) {
            const f32x4 acc = (mt == 0) ? z0 : (mt == 1) ? z1 : (mt == 2) ? z2 : z3;
            const int row0 = mt * 16 + rbase;
#pragma unroll
            for (int r = 0; r < 4; ++r) {
              const int row = row0 + r;
              if (row < 32) Zb[row * 68 + cc]              = acc[r];
              else          Zb[(row - 32) * 68 + 24 + cc]  = acc[r];
            }
          }
        }
      }
      __syncthreads();   // b2: Zb visible (and all Bt reads done)

      if (w < 2) {
        // GEMM2: out(32x32) = Z(32 x 48p64) * TB3
        f32x4 o0 = {}, o1 = {};
#pragma unroll
        for (int ks = 0; ks < 2; ++ks) {
#pragma unroll
          for (int mt = 0; mt < 2; ++mt) {
            const float4 q0 = *(const float4*)&Zb[(mt * 16 + c16) * 68 + ks * 32 + kb];
            const float4 q1 = *(const float4*)&Zb[(mt * 16 + c16) * 68 + ks * 32 + kb + 4];
            const float qf[8] = {q0.x, q0.y, q0.z, q0.w, q1.x, q1.y, q1.z, q1.w};
            half8 ah, al;
            split8(qf, ah, al);
            f32x4& acc = (mt == 0) ? o0 : o1;
            acc = __builtin_amdgcn_mfma_f32_16x16x32_f16(ah, tb3h[ks], acc, 0, 0, 0);
            acc = __builtin_amdgcn_mfma_f32_16x16x32_f16(ah, tb3l[ks], acc, 0, 0, 0);
            acc = __builtin_amdgcn_mfma_f32_16x16x32_f16(al, tb3h[ks], acc, 0, 0, 0);
          }
        }
        float* op = out + (size_t)(bc * 32 + m1) * 1024;
#pragma unroll
        for (int mt = 0; mt < 2; ++mt) {
          const f32x4 acc = (mt == 0) ? o0 : o1;
#pragma unroll
          for (int r = 0; r < 4; ++r) {
            const int m2 = mt * 16 + rbase + r;
            op[m2 * 32 + cc] = acc[r] * NORM_F;
          }
        }
      }
    }
  }

  // lazy-init flag: strictly after k_init_tw in stream order.
  if (tid == 0 && blockIdx.x == 0) g_twdone = 1;
}

extern "C" void kernel_launch(void* const* d_in, const int* in_sizes, int n_in,
                              void* d_out, int out_size, void* d_ws, size_t ws_size,
                              hipStream_t stream) {
  const float* x = (const float*)d_in[0];
  float* out = (float*)d_out;
  float2* V = (float2*)d_ws;                                   // 56,623,104 B
  float2* W = (float2*)((char*)d_ws + 56623104);               // 37,748,736 B

  k_init_tw <<<dim3(60), dim3(256), 0, stream>>>();
  k_mono    <<<dim3(256), dim3(192), 0, stream>>>(x, V, W, out);
}